// Round 1
// baseline (454.380 us; speedup 1.0000x reference)
//
#include <hip/hip_runtime.h>

#define BDIM 8192
#define KTOP 3
#define MARGIN 0.8f
#define TAU 0.1f
#define NEG_FILL -50.0f

// Insert x into descending-sorted triple (t1 >= t2 >= t3), keep top-3 of the 4.
__device__ __forceinline__ void insert3(float x, float& t1, float& t2, float& t3) {
    float a = fmaxf(t1, x);   // new t1
    float b = fminf(t1, x);   // loser of slot 1
    float c = fmaxf(t2, b);   // new t2
    float e = fminf(t2, b);   // loser of slot 2
    t3 = fmaxf(t3, e);        // new t3
    t2 = c;
    t1 = a;
}

__global__ __launch_bounds__(256) void row_topk_loss(const float* __restrict__ inp,
                                                     float* __restrict__ row_loss) {
    const int row = blockIdx.x;
    const int tid = threadIdx.x;
    const float4* rp = (const float4*)inp + (size_t)row * (BDIM / 4);
    const int diag4 = row >> 2;   // which float4 holds the diagonal element
    const int diagc = row & 3;    // which component within it

    float t1 = -1e30f, t2 = -1e30f, t3 = -1e30f;

#pragma unroll
    for (int w = 0; w < (BDIM / 4) / 256; ++w) {
        int c4 = tid + w * 256;
        float4 v = rp[c4];
        if (c4 == diag4) {            // rare: one float4 per row
            if      (diagc == 0) v.x = NEG_FILL;
            else if (diagc == 1) v.y = NEG_FILL;
            else if (diagc == 2) v.z = NEG_FILL;
            else                 v.w = NEG_FILL;
        }
        insert3(v.x, t1, t2, t3);
        insert3(v.y, t1, t2, t3);
        insert3(v.z, t1, t2, t3);
        insert3(v.w, t1, t2, t3);
    }

    // Wave(64)-level butterfly merge of triples.
#pragma unroll
    for (int off = 32; off > 0; off >>= 1) {
        float o1 = __shfl_xor(t1, off);
        float o2 = __shfl_xor(t2, off);
        float o3 = __shfl_xor(t3, off);
        insert3(o1, t1, t2, t3);
        insert3(o2, t1, t2, t3);
        insert3(o3, t1, t2, t3);
    }

    __shared__ float s1[4], s2[4], s3[4];
    const int wave = tid >> 6;
    if ((tid & 63) == 0) { s1[wave] = t1; s2[wave] = t2; s3[wave] = t3; }
    __syncthreads();

    if (tid == 0) {
#pragma unroll
        for (int w = 1; w < 4; ++w) {
            insert3(s1[w], t1, t2, t3);
            insert3(s2[w], t1, t2, t3);
            insert3(s3[w], t1, t2, t3);
        }
        // positive similarity = diagonal entry (target is eye(B))
        const float d = inp[(size_t)row * BDIM + row];

        float v[KTOP] = {t1, t2, t3};
        float loss[KTOP], x[KTOP];
        float xmax = -1e30f;
#pragma unroll
        for (int k = 0; k < KTOP; ++k) {
            loss[k] = fmaxf((v[k] - d) + MARGIN, 0.0f);
            float m = (loss[k] == 0.0f) ? NEG_FILL : v[k];
            x[k] = m * (1.0f / TAU);
            xmax = fmaxf(xmax, x[k]);
        }
        float esum = 0.0f, acc = 0.0f;
        float e[KTOP];
#pragma unroll
        for (int k = 0; k < KTOP; ++k) { e[k] = expf(x[k] - xmax); esum += e[k]; }
        float inv = 1.0f / esum;
#pragma unroll
        for (int k = 0; k < KTOP; ++k) acc += loss[k] * e[k] * inv;

        row_loss[row] = acc;
    }
}

__global__ __launch_bounds__(256) void reduce_mean(const float* __restrict__ row_loss,
                                                   float* __restrict__ out) {
    const int tid = threadIdx.x;
    float s = 0.0f;
    for (int i = tid; i < BDIM; i += 256) s += row_loss[i];
#pragma unroll
    for (int off = 32; off > 0; off >>= 1) s += __shfl_xor(s, off);
    __shared__ float ws[4];
    if ((tid & 63) == 0) ws[tid >> 6] = s;
    __syncthreads();
    if (tid == 0) out[0] = (ws[0] + ws[1] + ws[2] + ws[3]) * (1.0f / (float)(BDIM * KTOP));
}

extern "C" void kernel_launch(void* const* d_in, const int* in_sizes, int n_in,
                              void* d_out, int out_size, void* d_ws, size_t ws_size,
                              hipStream_t stream) {
    const float* inp = (const float*)d_in[0];
    // d_in[1] (target) is structurally eye(B); the diagonal is the positive mask.
    float* out = (float*)d_out;
    float* rows = (float*)d_ws;   // BDIM floats of scratch

    row_topk_loss<<<BDIM, 256, 0, stream>>>(inp, rows);
    reduce_mean<<<1, 256, 0, stream>>>(rows, out);
}

// Round 2
// 440.060 us; speedup vs baseline: 1.0325x; 1.0325x over previous
//
#include <hip/hip_runtime.h>

#define BDIM 8192
#define KTOP 3
#define MARGIN 0.8f
#define TAU 0.1f
#define NEG_FILL -50.0f

typedef float f32x4 __attribute__((ext_vector_type(4)));

// Insert x into descending-sorted triple (t1 >= t2 >= t3), keep top-3 of the 4.
__device__ __forceinline__ void insert3(float x, float& t1, float& t2, float& t3) {
    float a = fmaxf(t1, x);   // new t1
    float b = fminf(t1, x);   // loser of slot 1
    float c = fmaxf(t2, b);   // new t2
    float e = fminf(t2, b);   // loser of slot 2
    t3 = fmaxf(t3, e);        // new t3
    t2 = c;
    t1 = a;
}

__global__ __launch_bounds__(256) void row_topk_loss(const float* __restrict__ inp,
                                                     float* __restrict__ row_loss) {
    const int row = blockIdx.x;
    const int tid = threadIdx.x;
    const f32x4* rp = (const f32x4*)(inp + (size_t)row * BDIM);
    const int diag4 = row >> 2;   // which float4 holds the diagonal element
    const int diagc = row & 3;    // component within it

    // Four independent triples (one per vector lane) -> 4x shorter dep chain.
    float x1 = -1e30f, x2 = -1e30f, x3 = -1e30f;
    float y1 = -1e30f, y2 = -1e30f, y3 = -1e30f;
    float z1 = -1e30f, z2 = -1e30f, z3 = -1e30f;
    float w1 = -1e30f, w2 = -1e30f, w3 = -1e30f;

#pragma unroll
    for (int it = 0; it < (BDIM / 4) / 256; ++it) {
        const int c4 = tid + it * 256;
        f32x4 v = __builtin_nontemporal_load(rp + c4);
        if (c4 == diag4) v[diagc] = NEG_FILL;   // one float4 per row
        insert3(v.x, x1, x2, x3);
        insert3(v.y, y1, y2, y3);
        insert3(v.z, z1, z2, z3);
        insert3(v.w, w1, w2, w3);
    }

    // Merge the 4 component triples into one.
    float t1 = x1, t2 = x2, t3 = x3;
    insert3(y1, t1, t2, t3); insert3(y2, t1, t2, t3); insert3(y3, t1, t2, t3);
    insert3(z1, t1, t2, t3); insert3(z2, t1, t2, t3); insert3(z3, t1, t2, t3);
    insert3(w1, t1, t2, t3); insert3(w2, t1, t2, t3); insert3(w3, t1, t2, t3);

    // Wave(64)-level butterfly merge of triples.
#pragma unroll
    for (int off = 32; off > 0; off >>= 1) {
        float o1 = __shfl_xor(t1, off);
        float o2 = __shfl_xor(t2, off);
        float o3 = __shfl_xor(t3, off);
        insert3(o1, t1, t2, t3);
        insert3(o2, t1, t2, t3);
        insert3(o3, t1, t2, t3);
    }

    __shared__ float s1[4], s2[4], s3[4];
    const int wave = tid >> 6;
    if ((tid & 63) == 0) { s1[wave] = t1; s2[wave] = t2; s3[wave] = t3; }
    __syncthreads();

    if (tid == 0) {
#pragma unroll
        for (int w = 1; w < 4; ++w) {
            insert3(s1[w], t1, t2, t3);
            insert3(s2[w], t1, t2, t3);
            insert3(s3[w], t1, t2, t3);
        }
        // positive similarity = diagonal entry (target is eye(B))
        const float d = inp[(size_t)row * BDIM + row];

        float v[KTOP] = {t1, t2, t3};
        float loss[KTOP], x[KTOP];
        float xmax = -1e30f;
#pragma unroll
        for (int k = 0; k < KTOP; ++k) {
            loss[k] = fmaxf((v[k] - d) + MARGIN, 0.0f);
            float m = (loss[k] == 0.0f) ? NEG_FILL : v[k];
            x[k] = m * (1.0f / TAU);
            xmax = fmaxf(xmax, x[k]);
        }
        float esum = 0.0f, acc = 0.0f;
        float e[KTOP];
#pragma unroll
        for (int k = 0; k < KTOP; ++k) { e[k] = expf(x[k] - xmax); esum += e[k]; }
        float inv = 1.0f / esum;
#pragma unroll
        for (int k = 0; k < KTOP; ++k) acc += loss[k] * e[k] * inv;

        row_loss[row] = acc;
    }
}

__global__ __launch_bounds__(256) void reduce_mean(const float* __restrict__ row_loss,
                                                   float* __restrict__ out) {
    const int tid = threadIdx.x;
    float s = 0.0f;
    for (int i = tid; i < BDIM; i += 256) s += row_loss[i];
#pragma unroll
    for (int off = 32; off > 0; off >>= 1) s += __shfl_xor(s, off);
    __shared__ float ws[4];
    if ((tid & 63) == 0) ws[tid >> 6] = s;
    __syncthreads();
    if (tid == 0) out[0] = (ws[0] + ws[1] + ws[2] + ws[3]) * (1.0f / (float)(BDIM * KTOP));
}

extern "C" void kernel_launch(void* const* d_in, const int* in_sizes, int n_in,
                              void* d_out, int out_size, void* d_ws, size_t ws_size,
                              hipStream_t stream) {
    const float* inp = (const float*)d_in[0];
    // d_in[1] (target) is structurally eye(B); the diagonal is the positive mask.
    float* out = (float*)d_out;
    float* rows = (float*)d_ws;   // BDIM floats of scratch

    row_topk_loss<<<BDIM, 256, 0, stream>>>(inp, rows);
    reduce_mean<<<1, 256, 0, stream>>>(rows, out);
}

// Round 3
// 427.269 us; speedup vs baseline: 1.0635x; 1.0299x over previous
//
#include <hip/hip_runtime.h>

#define BDIM 8192
#define KTOP 3
#define MARGIN 0.8f
#define TAU 0.1f
#define NEG_FILL -50.0f

typedef float f32x4 __attribute__((ext_vector_type(4)));

// Insert x into descending-sorted triple (t1 >= t2 >= t3), keep top-3 of the 4.
__device__ __forceinline__ void insert3(float x, float& t1, float& t2, float& t3) {
    float a = fmaxf(t1, x);   // new t1
    float b = fminf(t1, x);   // loser of slot 1
    float c = fmaxf(t2, b);   // new t2
    float e = fminf(t2, b);   // loser of slot 2
    t3 = fmaxf(t3, e);        // new t3
    t2 = c;
    t1 = a;
}

// One wave (64 lanes) per row; 4 waves per block. No __syncthreads anywhere.
__global__ __launch_bounds__(256) void row_topk_loss(const float* __restrict__ inp,
                                                     float* __restrict__ row_loss) {
    const int wave_in_blk = threadIdx.x >> 6;
    const int lane = threadIdx.x & 63;
    const int row = blockIdx.x * 4 + wave_in_blk;
    const f32x4* rp = (const f32x4*)(inp + (size_t)row * BDIM);
    const int diag4 = row >> 2;   // which float4 holds the diagonal element
    const int diagc = row & 3;    // component within it

    // Four independent triples (one per vector component).
    float x1 = -1e30f, x2 = -1e30f, x3 = -1e30f;
    float y1 = -1e30f, y2 = -1e30f, y3 = -1e30f;
    float z1 = -1e30f, z2 = -1e30f, z3 = -1e30f;
    float w1 = -1e30f, w2 = -1e30f, w3 = -1e30f;

#pragma unroll
    for (int it = 0; it < (BDIM / 4) / 64; ++it) {   // 32 iterations
        const int c4 = lane + it * 64;               // coalesced across the wave
        f32x4 v = __builtin_nontemporal_load(rp + c4);
        if (c4 == diag4) v[diagc] = NEG_FILL;        // one float4 per row
        insert3(v.x, x1, x2, x3);
        insert3(v.y, y1, y2, y3);
        insert3(v.z, z1, z2, z3);
        insert3(v.w, w1, w2, w3);
    }

    // Merge the 4 component triples into one.
    float t1 = x1, t2 = x2, t3 = x3;
    insert3(y1, t1, t2, t3); insert3(y2, t1, t2, t3); insert3(y3, t1, t2, t3);
    insert3(z1, t1, t2, t3); insert3(z2, t1, t2, t3); insert3(z3, t1, t2, t3);
    insert3(w1, t1, t2, t3); insert3(w2, t1, t2, t3); insert3(w3, t1, t2, t3);

    // Wave(64)-level butterfly merge of triples.
#pragma unroll
    for (int off = 32; off > 0; off >>= 1) {
        float o1 = __shfl_xor(t1, off);
        float o2 = __shfl_xor(t2, off);
        float o3 = __shfl_xor(t3, off);
        insert3(o1, t1, t2, t3);
        insert3(o2, t1, t2, t3);
        insert3(o3, t1, t2, t3);
    }

    if (lane == 0) {
        // positive similarity = diagonal entry (target is eye(B))
        const float d = inp[(size_t)row * BDIM + row];

        float v[KTOP] = {t1, t2, t3};
        float loss[KTOP], x[KTOP];
        float xmax = -1e30f;
#pragma unroll
        for (int k = 0; k < KTOP; ++k) {
            loss[k] = fmaxf((v[k] - d) + MARGIN, 0.0f);
            float m = (loss[k] == 0.0f) ? NEG_FILL : v[k];
            x[k] = m * (1.0f / TAU);
            xmax = fmaxf(xmax, x[k]);
        }
        float esum = 0.0f, acc = 0.0f;
        float e[KTOP];
#pragma unroll
        for (int k = 0; k < KTOP; ++k) { e[k] = expf(x[k] - xmax); esum += e[k]; }
        float inv = 1.0f / esum;
#pragma unroll
        for (int k = 0; k < KTOP; ++k) acc += loss[k] * e[k] * inv;

        row_loss[row] = acc;
    }
}

__global__ __launch_bounds__(256) void reduce_mean(const float* __restrict__ row_loss,
                                                   float* __restrict__ out) {
    const int tid = threadIdx.x;
    const f32x4* rp = (const f32x4*)row_loss;
    float s = 0.0f;
#pragma unroll
    for (int i = 0; i < (BDIM / 4) / 256; ++i) {     // 8 float4 per thread
        f32x4 v = rp[tid + i * 256];
        s += (v.x + v.y) + (v.z + v.w);
    }
#pragma unroll
    for (int off = 32; off > 0; off >>= 1) s += __shfl_xor(s, off);
    __shared__ float ws[4];
    if ((tid & 63) == 0) ws[tid >> 6] = s;
    __syncthreads();
    if (tid == 0) out[0] = (ws[0] + ws[1] + ws[2] + ws[3]) * (1.0f / (float)(BDIM * KTOP));
}

extern "C" void kernel_launch(void* const* d_in, const int* in_sizes, int n_in,
                              void* d_out, int out_size, void* d_ws, size_t ws_size,
                              hipStream_t stream) {
    const float* inp = (const float*)d_in[0];
    // d_in[1] (target) is structurally eye(B); the diagonal is the positive mask.
    float* out = (float*)d_out;
    float* rows = (float*)d_ws;   // BDIM floats of scratch

    row_topk_loss<<<BDIM / 4, 256, 0, stream>>>(inp, rows);
    reduce_mean<<<1, 256, 0, stream>>>(rows, out);
}